// Round 5
// baseline (391.057 us; speedup 1.0000x reference)
//
#include <hip/hip_runtime.h>
#include <stdint.h>

// Problem constants
#define KCOMP 65536
#define DDIM  256
#define ODIM  256
#define BROWS 1024
#define NCB   512            // comp-blocks: KCOMP / 128 comps per block
#define NBLK  512            // main grid: one block per comp-block (no row split)
#define LOG2PI_TERM 235.2482645f   // 0.5 * D * ln(2*pi)

typedef float f32x4 __attribute__((ext_vector_type(4)));
typedef __bf16 bf16x8 __attribute__((ext_vector_type(8)));
typedef unsigned int u32;
typedef unsigned long long u64;
typedef unsigned short u16;

typedef __attribute__((address_space(1))) const u32 gconst_u32;
typedef __attribute__((address_space(3))) u32 lds_u32;

__device__ __forceinline__ u16 f2bf(float f) {
  u32 b = __float_as_uint(f);
  b += 0x7FFFu + ((b >> 16) & 1u);
  return (u16)(b >> 16);
}
// monotone float->u32 key (finalize only — main_gemm scores are all-negative
// so raw bits with unsigned-MIN are already order-correct)
__device__ __forceinline__ u32 fkey(float f) {
  u32 b = __float_as_uint(f);
  return b ^ ((b >> 31) ? 0xFFFFFFFFu : 0x80000000u);
}

// DPP row_ror:n (rotate within 16-lane rows) — used by finalize's reductions.
#define DPP_ROR1 0x121
#define DPP_ROR2 0x122
#define DPP_ROR4 0x124
#define DPP_ROR8 0x128

// ws layout (bytes). Total ~9 MB.
#define WS_A     0                          // 1 MB  A frag-linear [64 tile][16 cc][64 lane][16B]
#define WS_KEY   (1u << 20)                 // 8 MB  cand keys [1024 row][512 cb][4]

// ---------------------------------------------------------------------------
// Kernel 1: A features. kappa=2d -> x_d^2 ; kappa=2d+1 -> -2 x_d (MFMA A layout).
__global__ void prep_A(const float* __restrict__ x, u16* __restrict__ A) {
  int l = threadIdx.x & 63;
  int wv = threadIdx.x >> 6;
  int t = blockIdx.x;                 // m16 tile 0..63
  int row = t * 16 + (l & 15);
  for (int u = 0; u < 4; ++u) {
    int cc = wv * 4 + u;              // 0..15
    int d0 = cc * 16 + ((l >> 4) << 2);
    float4 xv = *(const float4*)(x + (size_t)row * DDIM + d0);
    float xs[4] = {xv.x, xv.y, xv.z, xv.w};
    uint4 v;
    u32 wds[4];
    for (int e = 0; e < 4; ++e)
      wds[e] = (u32)f2bf(xs[e] * xs[e]) | ((u32)f2bf(-2.0f * xs[e]) << 16);
    v.x = wds[0]; v.y = wds[1]; v.z = wds[2]; v.w = wds[3];
    *(uint4*)(A + ((size_t)(t * 16 + cc) * 64 + l) * 8) = v;
  }
}

// ---------------------------------------------------------------------------
// Kernel 2: main GEMM + fused W-conversion + fused selection.
// Grid 512 = one block per 128 comps; block sweeps ALL 1024 rows.
// ROUND-10 CHANGE (row-split waves): stage time proved invariant (~12k cyc)
// to occupancy (r2: 2x -> +3%), LDS volume (r1 vs r2: 2x -> 0%), and barrier
// scheduling (r4 counted vmcnt -> -4%). The untouched knob: per-wave LDS
// READ REDUNDANCY — every wave read all 32 staged rows. Now waves partition
// BOTH axes: wave w -> row-tile wt=w>>2 (16 rows), comp-group wc=w&3
// (32 comps, wf[2][16] = 128 VGPRs). Per-wave ds_read_b128 per stage: 32 ->
// 16; block LDS-read volume 4x down vs r2. Selection contract = r1's
// (top-2 per 32 comps per wave, 8 cands/row). Cost: ~190 VGPR -> 2
// waves/SIMD, 1 block/CU (r1/r2 showed occupancy is nearly free).
// Barrier structure reverted to r2's known-good single __syncthreads
// (r4's two-barrier cost 6 us).
__global__ __launch_bounds__(512, 2)
void main_gemm(const u16* __restrict__ A_ws, const float* __restrict__ mean,
               const float* __restrict__ stdd, u32* __restrict__ ckey) {
  // union: [0,66560) = per-wave conversion scratch (8 x 8320 B) in prologue,
  //        [0,65536) = A double-buffer (2 bufs x 32 cells x 1 KB) in main loop
  __shared__ __align__(16) char lds_raw[66560];
  __shared__ u32 wsel[2][32][9];       // [buf][row][4 comp-groups x 2 + pad]
  int tid = threadIdx.x, l = tid & 63, w = tid >> 6;   // w in [0,8)
  int nb = blockIdx.x;                 // comp-block 0..511
  int p = l & 15, q = l >> 4;
  int wt = w >> 2;                     // row-tile 0/1 (16 rows each)
  int wc = w & 3;                      // comp-group 0..3 (32 comps each)

  u32 kid0 = (u32)(wc * 32 + q * 4);   // local comp id base (+gs*16+i), <128

  // ---- prologue: build wf[2][16] B-frags (pre-scaled by -0.5) + mycv ----
  // four rounds of 8 comps each through an 8-comp scratch (8320 B/wave).
  // Waves w and w+4 convert the same 32 comps (cache-deduped fetch).
  bf16x8 wf[2][16];
  float myc[2] = {0.f, 0.f};
  f32x4 mycv[2];
  {
    u32* scr = (u32*)(lds_raw + w * 8320);   // [8 comps][260 dwords] padded
    int p8 = l & 7, q8 = l >> 3;             // q8 in [0,8): 32-dim eighth
    int g0 = nb * 128 + wc * 32;
#pragma unroll
    for (int rr = 0; rr < 4; ++rr) {
      int comp = g0 + rr * 8 + p8;
      const float* mrow = mean + (size_t)comp * DDIM + q8 * 32;
      const float* srow = stdd + (size_t)comp * DDIM + q8 * 32;
      float gsum = 0.f;
#pragma unroll
      for (int i = 0; i < 8; ++i) {
        float4 m4 = *(const float4*)(mrow + 4 * i);
        float4 s4 = *(const float4*)(srow + 4 * i);
        float ms[4] = {m4.x, m4.y, m4.z, m4.w};
        float ss[4] = {s4.x, s4.y, s4.z, s4.w};
        u32 wd[4];
#pragma unroll
        for (int e = 0; e < 4; ++e) {
          float iv = __builtin_amdgcn_rcpf(ss[e] * ss[e]);
          float miv = ms[e] * iv;
          // store -0.5*iv | -0.5*miv so dot(A,W) = -0.5*quad directly
          wd[e] = (u32)f2bf(-0.5f * iv) | ((u32)f2bf(-0.5f * miv) << 16);
          gsum -= 0.5f * ms[e] * miv + __logf(ss[e]);
        }
        uint4 v; v.x = wd[0]; v.y = wd[1]; v.z = wd[2]; v.w = wd[3];
        *(uint4*)(scr + p8 * 260 + q8 * 32 + i * 4) = v;   // [comp][dim]
      }
      // sum the 8 dim-eighth partials of comp (rr*8 + p8)
      gsum += __shfl_xor(gsum, 8);
      gsum += __shfl_xor(gsum, 16);
      gsum += __shfl_xor(gsum, 32);
      // lane's comp for group gs is gs*16+p; its scratch slot is p&7 and it
      // lives in round rr = (gs*16+p)>>3. Wave-local in-order LDS: reads of
      // round rr complete before round rr+1's overwrites.
#pragma unroll
      for (int gs = 0; gs < 2; ++gs) {
        if (((gs * 16 + p) >> 3) == rr) {
          myc[gs] = gsum - LOG2PI_TERM;
#pragma unroll
          for (int cc = 0; cc < 16; ++cc)
            wf[gs][cc] = *(const bf16x8*)(scr + (p & 7) * 260 + cc * 16 + q * 4);
        }
      }
    }
    // redistribute myc: lane (q,p) needs myc of comps gs*16 + q*4+i
    // (held by lane q*4+i, whose p == q*4+i)
#pragma unroll
    for (int gs = 0; gs < 2; ++gs)
#pragma unroll
      for (int i = 0; i < 4; ++i)
        mycv[gs][i] = __shfl(myc[gs], q * 4 + i);
  }
  __syncthreads();                     // scratch region now reused as Ash

#define ASHP(B, CELL) (lds_raw + ((size_t)(B) * 32 + (CELL)) * 1024)

  // stage S (2 m16-tiles = 32 cells of 1 KB) into buf B; wave stages 4 cells
#define ISSUE(S, B)                                                           \
  {                                                                           \
    _Pragma("unroll")                                                         \
    for (int u = 0; u < 4; ++u) {                                             \
      int cell = w * 4 + u;                                                   \
      const u16* gsrc = A_ws +                                                \
        ((size_t)((S) * 2 + (cell >> 4)) * 16 + (cell & 15)) * 512            \
        + (size_t)l * 8;                                                      \
      __builtin_amdgcn_global_load_lds((gconst_u32*)gsrc,                     \
          (lds_u32*)ASHP(B, cell), 16, 0, 0);                                 \
    }                                                                         \
  }

  // merge 8 wsel keys (min = best) -> 4 smallest for 32 rows; emit inverted
#define MERGE_EMIT(ST, B)                                                     \
  {                                                                           \
    int r = tid;                                                              \
    u32 top[4] = {~0u, ~0u, ~0u, ~0u};                                        \
    _Pragma("unroll")                                                         \
    for (int j = 0; j < 8; ++j) {                                             \
      u32 key = wsel[B][r][j];                                                \
      if (key < top[3]) {                                                     \
        top[3] = key;                                                         \
        for (int z = 3; z > 0 && top[z] < top[z - 1]; --z) {                  \
          u32 tt = top[z]; top[z] = top[z - 1]; top[z - 1] = tt;              \
        }                                                                     \
      }                                                                       \
    }                                                                         \
    int rowg = (ST) * 32 + r;                                                 \
    uint4 ov; ov.x = ~top[0]; ov.y = ~top[1]; ov.z = ~top[2]; ov.w = ~top[3]; \
    *(uint4*)&ckey[((size_t)rowg * NCB + nb) * 4] = ov;                       \
  }

  ISSUE(0, 0)
  for (int s = 0; s < 32; ++s) {
    int pb = s & 1;
    __syncthreads();                   // buf pb staged; wsel[pb^1] complete
    if (s < 31) ISSUE(s + 1, pb ^ 1)
    if (s > 0 && tid < 32) MERGE_EMIT(s - 1, pb ^ 1)

    f32x4 ac0 = mycv[0];               // [comp-group]; init = myc
    f32x4 ac1 = mycv[1];
    __builtin_amdgcn_s_setprio(1);
#pragma unroll
    for (int cc = 0; cc < 16; ++cc) {
      // wave reads ONLY its row-tile's frags: 16 ds_read_b128 per stage
      bf16x8 a = *(const bf16x8*)(ASHP(pb, wt * 16 + cc) + (size_t)l * 16);
      // SWAPPED operands: W as A-operand (comps = M), rows as B-operand (N)
      ac0 = __builtin_amdgcn_mfma_f32_16x16x32_bf16(wf[0][cc], a, ac0, 0, 0, 0);
      ac1 = __builtin_amdgcn_mfma_f32_16x16x32_bf16(wf[1][cc], a, ac1, 0, 0, 0);
    }
    __builtin_amdgcn_s_setprio(0);

    // selection: lane holds 8 comps (2 gs x 4 reg) of x-row wt*16+p.
    // scores are the ac values directly (all <= -235 < 0): unsigned MIN = best.
#define UMIN(a, b) ((a) < (b) ? (a) : (b))
#define UMAX(a, b) ((a) < (b) ? (b) : (a))
    {
      u32 a1_, a2_, b1_, b2_;
      {
        u32 k0 = (__float_as_uint(ac0[0]) & 0xFFFFFF00u) | (kid0 + 0);
        u32 k1 = (__float_as_uint(ac0[1]) & 0xFFFFFF00u) | (kid0 + 1);
        u32 k2 = (__float_as_uint(ac0[2]) & 0xFFFFFF00u) | (kid0 + 2);
        u32 k3 = (__float_as_uint(ac0[3]) & 0xFFFFFF00u) | (kid0 + 3);
        u32 l0 = UMIN(k0, k1), h0 = UMAX(k0, k1);
        u32 l1 = UMIN(k2, k3), h1 = UMAX(k2, k3);
        a1_ = UMIN(l0, l1);
        a2_ = UMIN(UMAX(l0, l1), UMIN(h0, h1));
      }
      {
        u32 k0 = (__float_as_uint(ac1[0]) & 0xFFFFFF00u) | (kid0 + 16);
        u32 k1 = (__float_as_uint(ac1[1]) & 0xFFFFFF00u) | (kid0 + 17);
        u32 k2 = (__float_as_uint(ac1[2]) & 0xFFFFFF00u) | (kid0 + 18);
        u32 k3 = (__float_as_uint(ac1[3]) & 0xFFFFFF00u) | (kid0 + 19);
        u32 l0 = UMIN(k0, k1), h0 = UMAX(k0, k1);
        u32 l1 = UMIN(k2, k3), h1 = UMAX(k2, k3);
        b1_ = UMIN(l0, l1);
        b2_ = UMIN(UMAX(l0, l1), UMIN(h0, h1));
      }
      // merge the two sorted pairs -> wave-local top-2 of 8
      u32 m1 = UMIN(a1_, b1_);
      u32 m2 = UMIN(UMAX(a1_, b1_), UMIN(a2_, b2_));
      // merge across the 4 q-lanes holding the same x-row: xor16 then xor32
      {
        u32 o1 = (u32)__shfl_xor((int)m1, 16);
        u32 o2 = (u32)__shfl_xor((int)m2, 16);
        u32 lo = UMIN(m1, o1), hi = UMAX(m1, o1), mn = UMIN(m2, o2);
        m1 = lo; m2 = UMIN(hi, mn);
      }
      {
        u32 o1 = (u32)__shfl_xor((int)m1, 32);
        u32 o2 = (u32)__shfl_xor((int)m2, 32);
        u32 lo = UMIN(m1, o1), hi = UMAX(m1, o1), mn = UMIN(m2, o2);
        m1 = lo; m2 = UMIN(hi, mn);
      }
      if (q == 0) {
        int r = wt * 16 + p;
        wsel[pb][r][wc * 2] = m1;
        wsel[pb][r][wc * 2 + 1] = m2;
      }
    }
#undef UMIN
#undef UMAX
  }
  __syncthreads();
  if (tid < 32) MERGE_EMIT(31, 1)
#undef ISSUE
#undef MERGE_EMIT
#undef ASHP
}

// ---------------------------------------------------------------------------
// Kernel 3: per-row finalize. 2048 keys -> 4 parallel per-wave exact top-16
// via u32 ext-keys + DPP/shfl arg-max; exact fp32 lp for 64; exact top-32 +
// softmax; weighted gather.
__global__ __launch_bounds__(256)
void finalize(const float* __restrict__ x, const float* __restrict__ mean,
              const float* __restrict__ stdd, const float* __restrict__ outs,
              const u32* __restrict__ ckey, float* __restrict__ out) {
  __shared__ u32 cksh[2048];
  __shared__ float xr[256];
  __shared__ float part[256];
  __shared__ int selk[64];
  __shared__ float ew[32];
  __shared__ int kf[32];
  __shared__ float invs_sh;
  int tid = threadIdx.x, l = tid & 63, v = tid >> 6;
  int row = blockIdx.x;

  for (int i = tid; i < 2048; i += 256)
    cksh[i] = ckey[(size_t)row * 2048 + i];
  xr[tid] = x[(size_t)row * DDIM + tid];
  __syncthreads();

  // 64-lane max reduce on u32 (4 DPP rotations + 2 shfl)
#define REDUCE_MAX(m)                                                         \
  {                                                                           \
    u32 o;                                                                    \
    o = (u32)__builtin_amdgcn_mov_dpp((int)m, DPP_ROR1, 0xf, 0xf, false);     \
    m = m > o ? m : o;                                                        \
    o = (u32)__builtin_amdgcn_mov_dpp((int)m, DPP_ROR2, 0xf, 0xf, false);     \
    m = m > o ? m : o;                                                        \
    o = (u32)__builtin_amdgcn_mov_dpp((int)m, DPP_ROR4, 0xf, 0xf, false);     \
    m = m > o ? m : o;                                                        \
    o = (u32)__builtin_amdgcn_mov_dpp((int)m, DPP_ROR8, 0xf, 0xf, false);     \
    m = m > o ? m : o;                                                        \
    o = (u32)__shfl_xor((int)m, 16); m = m > o ? m : o;                       \
    o = (u32)__shfl_xor((int)m, 32); m = m > o ? m : o;                       \
  }

  {  // wave v: exact top-16 of its 512 cands
    u32 ext[8];
#pragma unroll
    for (int i = 0; i < 8; ++i) {
      int j = v * 512 + i * 64 + l;
      ext[i] = (cksh[j] & 0xFFFFFE00u) | ((u32)l << 3) | (u32)i;
    }
#define CSW(a, b) { if (ext[a] < ext[b]) { u32 t = ext[a]; ext[a] = ext[b]; ext[b] = t; } }
    CSW(0,1) CSW(2,3) CSW(4,5) CSW(6,7)
    CSW(0,2) CSW(1,3) CSW(4,6) CSW(5,7)
    CSW(1,2) CSW(5,6)
    CSW(0,4) CSW(1,5) CSW(2,6) CSW(3,7)
    CSW(2,4) CSW(3,5)
    CSW(1,2) CSW(3,4) CSW(5,6)
#undef CSW
    for (int it = 0; it < 16; ++it) {
      u32 m = ext[0];
      REDUCE_MAX(m)
      if (m == ext[0]) {
#pragma unroll
        for (int z = 0; z < 7; ++z) ext[z] = ext[z + 1];
        ext[7] = 0;
      }
      if (l == 0) {
        int wl = (int)((m >> 3) & 63u), wi = (int)(m & 7u);
        int j = v * 512 + wi * 64 + wl;
        selk[v * 16 + it] = (int)((u32)(j >> 2) * 128u + (~cksh[j] & 0x7Fu));
      }
    }
  }
  __syncthreads();

  {  // exact fp32 lp for 64 cands, 4 threads each
    int j = tid >> 2, qq = tid & 3;
    int k = selk[j];
    const float* mr = mean + (size_t)k * DDIM + qq * 64;
    const float* sr = stdd + (size_t)k * DDIM + qq * 64;
    float s2 = 0.f, ls = 0.f;
    for (int i = 0; i < 16; ++i) {
      float4 m4 = *(const float4*)(mr + 4 * i);
      float4 s4 = *(const float4*)(sr + 4 * i);
      float4 x4 = *(const float4*)(&xr[qq * 64 + 4 * i]);
      { float is = 1.f / s4.x; float df = (x4.x - m4.x) * is; s2 += df * df; ls += __logf(s4.x); }
      { float is = 1.f / s4.y; float df = (x4.y - m4.y) * is; s2 += df * df; ls += __logf(s4.y); }
      { float is = 1.f / s4.z; float df = (x4.z - m4.z) * is; s2 += df * df; ls += __logf(s4.z); }
      { float is = 1.f / s4.w; float df = (x4.w - m4.w) * is; s2 += df * df; ls += __logf(s4.w); }
    }
    part[tid] = -0.5f * s2 - ls;
  }
  __syncthreads();

  if (tid < 64) {                      // exact top-32 + softmax (wave 0)
    float lp0 = part[l * 4] + part[l * 4 + 1] + part[l * 4 + 2] +
                part[l * 4 + 3] - LOG2PI_TERM;
    u32 ext = (fkey(lp0) & 0xFFFFFFC0u) | (u32)l;
    float maxlp = 0.f, ssum = 0.f;
    for (int it = 0; it < 32; ++it) {
      u32 m = ext;
      REDUCE_MAX(m)
      int j = (int)(m & 63u);
      u32 vb = m & 0xFFFFFFC0u;
      vb ^= (vb >> 31) ? 0x80000000u : 0xFFFFFFFFu;
      float lp = __uint_as_float(vb);
      if (it == 0) maxlp = lp;
      float e = __expf(lp - maxlp);
      ssum += e;
      if (l == 0) { ew[it] = e; kf[it] = selk[j]; }
      if (j == l) ext = 0;
    }
    if (l == 0) invs_sh = 1.0f / ssum;
  }
  __syncthreads();
#undef REDUCE_MAX

  {  // weighted gather: one output element per thread
    float a = 0.f;
    for (int i = 0; i < 32; ++i)
      a += ew[i] * outs[(size_t)kf[i] * ODIM + tid];
    out[(size_t)row * ODIM + tid] = a * invs_sh;
  }
}

// ---------------------------------------------------------------------------
extern "C" void kernel_launch(void* const* d_in, const int* in_sizes, int n_in,
                              void* d_out, int out_size, void* d_ws, size_t ws_size,
                              hipStream_t stream) {
  const float* x = (const float*)d_in[0];
  const float* mean = (const float*)d_in[1];
  const float* stdd = (const float*)d_in[2];
  const float* outs = (const float*)d_in[3];
  char* ws = (char*)d_ws;
  u16* A_ws = (u16*)(ws + WS_A);
  u32* ckey = (u32*)(ws + WS_KEY);

  prep_A<<<64, 256, 0, stream>>>(x, A_ws);
  main_gemm<<<NBLK, 512, 0, stream>>>(A_ws, mean, stdd, ckey);
  finalize<<<BROWS, 256, 0, stream>>>(x, mean, stdd, outs, ckey,
                                      (float*)d_out);
}

// Round 6
// 387.456 us; speedup vs baseline: 1.0093x; 1.0093x over previous
//
#include <hip/hip_runtime.h>
#include <stdint.h>

// Problem constants
#define KCOMP 65536
#define DDIM  256
#define ODIM  256
#define BROWS 1024
#define NCB   512            // comp-blocks: KCOMP / 128 comps per block
#define NBLK  512            // main grid: one block per comp-block (no row split)
#define LOG2PI_TERM 235.2482645f   // 0.5 * D * ln(2*pi)

typedef float f32x4 __attribute__((ext_vector_type(4)));
typedef __bf16 bf16x8 __attribute__((ext_vector_type(8)));
typedef unsigned int u32;
typedef unsigned long long u64;
typedef unsigned short u16;

__device__ __forceinline__ u16 f2bf(float f) {
  u32 b = __float_as_uint(f);
  b += 0x7FFFu + ((b >> 16) & 1u);
  return (u16)(b >> 16);
}
// monotone float->u32 key (finalize only — main_gemm scores are all-negative
// so raw bits with unsigned-MIN are already order-correct)
__device__ __forceinline__ u32 fkey(float f) {
  u32 b = __float_as_uint(f);
  return b ^ ((b >> 31) ? 0xFFFFFFFFu : 0x80000000u);
}

// DPP row_ror:n (rotate within 16-lane rows) — used by finalize's reductions.
#define DPP_ROR1 0x121
#define DPP_ROR2 0x122
#define DPP_ROR4 0x124
#define DPP_ROR8 0x128

// ws layout (bytes). Total ~9 MB.
#define WS_A     0                          // 1 MB  A frag-linear [64 tile][16 cc][64 lane][16B]
#define WS_KEY   (1u << 20)                 // 8 MB  cand keys [1024 row][512 cb][4]

// ---------------------------------------------------------------------------
// Kernel 1: A features. kappa=2d -> x_d^2 ; kappa=2d+1 -> -2 x_d (MFMA A layout).
__global__ void prep_A(const float* __restrict__ x, u16* __restrict__ A) {
  int l = threadIdx.x & 63;
  int wv = threadIdx.x >> 6;
  int t = blockIdx.x;                 // m16 tile 0..63
  int row = t * 16 + (l & 15);
  for (int u = 0; u < 4; ++u) {
    int cc = wv * 4 + u;              // 0..15
    int d0 = cc * 16 + ((l >> 4) << 2);
    float4 xv = *(const float4*)(x + (size_t)row * DDIM + d0);
    float xs[4] = {xv.x, xv.y, xv.z, xv.w};
    uint4 v;
    u32 wds[4];
    for (int e = 0; e < 4; ++e)
      wds[e] = (u32)f2bf(xs[e] * xs[e]) | ((u32)f2bf(-2.0f * xs[e]) << 16);
    v.x = wds[0]; v.y = wds[1]; v.z = wds[2]; v.w = wds[3];
    *(uint4*)(A + ((size_t)(t * 16 + cc) * 64 + l) * 8) = v;
  }
}

// ---------------------------------------------------------------------------
// Kernel 2: main GEMM + fused W-conversion + fused selection.
// Grid 512 = one block per 128 comps; block sweeps ALL 1024 rows.
// ROUND-11 CHANGE (drop A-staging; cache-direct reads): r5 refuted the
// LDS-volume theory (LDS busy ~11%, still slower); r1/r2/r5 triangle shows
// the wall is the staged-buffer barrier convoy + vmcnt drain. A_ws is 1 MB
// (L2/L3-resident; 32 KB/stage = one L1) — per guide common-mistake #7,
// staging cache-fit data is pure overhead. Each wave now reads its MFMA
// A-frags DIRECTLY from A_ws via plain global loads (same addrs across
// waves -> L1 broadcast; L2 demand ~256 B/cyc/XCD << 1.9 KB/cyc ceiling).
// The per-stage barrier survives only for the wsel handoff and waits only
// lgkmcnt(0): VGPR loads are wave-private, so NO vmem drain anywhere —
// the load pipeline flows across barriers. launch_bounds(512,4) forces
// <=128 VGPR (occupancy 16 waves/CU preserved; compiler throttles load
// hoisting to fit rather than spill).
__global__ __launch_bounds__(512, 4)
void main_gemm(const u16* __restrict__ A_ws, const float* __restrict__ mean,
               const float* __restrict__ stdd, u32* __restrict__ ckey) {
  // lds_raw: per-wave conversion scratch (8 x 8320 B) in prologue only
  __shared__ __align__(16) char lds_raw[66560];
  __shared__ u32 wsel[2][32][17];      // [buf][row][8 waves x 2 + pad]
  int tid = threadIdx.x, l = tid & 63, w = tid >> 6;   // w in [0,8)
  int nb = blockIdx.x;                 // comp-block 0..511
  int p = l & 15, q = l >> 4;

  u32 kid0 = (u32)(w * 16 + q * 4);    // local comp id base for this lane

  // ---- prologue: build wf[16] B-frags (pre-scaled by -0.5) + mycv ----
  // two rounds of 8 comps each through an 8-comp scratch (8320 B/wave)
  bf16x8 wf[16];
  float myc0;
  f32x4 mycv;
  {
    u32* scr = (u32*)(lds_raw + w * 8320);   // [8 comps][260 dwords] padded
    int p8 = l & 7, q8 = l >> 3;             // q8 in [0,8): 32-dim eighth
#pragma unroll
    for (int rr = 0; rr < 2; ++rr) {
      int comp = (nb * 8 + w) * 16 + rr * 8 + p8;
      const float* mrow = mean + (size_t)comp * DDIM + q8 * 32;
      const float* srow = stdd + (size_t)comp * DDIM + q8 * 32;
      float gsum = 0.f;
#pragma unroll
      for (int i = 0; i < 8; ++i) {
        float4 m4 = *(const float4*)(mrow + 4 * i);
        float4 s4 = *(const float4*)(srow + 4 * i);
        float ms[4] = {m4.x, m4.y, m4.z, m4.w};
        float ss[4] = {s4.x, s4.y, s4.z, s4.w};
        u32 wd[4];
#pragma unroll
        for (int e = 0; e < 4; ++e) {
          float iv = __builtin_amdgcn_rcpf(ss[e] * ss[e]);
          float miv = ms[e] * iv;
          // store -0.5*iv | -0.5*miv so dot(A,W) = -0.5*quad directly
          wd[e] = (u32)f2bf(-0.5f * iv) | ((u32)f2bf(-0.5f * miv) << 16);
          gsum -= 0.5f * ms[e] * miv + __logf(ss[e]);
        }
        uint4 v; v.x = wd[0]; v.y = wd[1]; v.z = wd[2]; v.w = wd[3];
        *(uint4*)(scr + p8 * 260 + q8 * 32 + i * 4) = v;   // [comp][dim]
      }
      // sum the 8 dim-eighth partials of comp p8 (lanes sharing l&7)
      gsum += __shfl_xor(gsum, 8);
      gsum += __shfl_xor(gsum, 16);
      gsum += __shfl_xor(gsum, 32);
      // lanes whose comp (p = l&15) lives in this round read their frags now
      // (wave-local in-order LDS; round rr+1 overwrites the scratch)
      if ((p >> 3) == rr) {
        myc0 = gsum - LOG2PI_TERM;
#pragma unroll
        for (int cc = 0; cc < 16; ++cc)
          wf[cc] = *(const bf16x8*)(scr + (p & 7) * 260 + cc * 16 + q * 4);
      }
    }
    // redistribute myc: lane (q,p) needs myc of comps q*4+i (held by lane q*4+i)
#pragma unroll
    for (int i = 0; i < 4; ++i)
      mycv[i] = __shfl(myc0, q * 4 + i);
  }
  __syncthreads();

  // merge 16 wsel keys (min = best) -> 4 smallest for 32 rows; emit inverted
#define MERGE_EMIT(ST, B)                                                     \
  {                                                                           \
    int r = tid;                                                              \
    u32 top[4] = {~0u, ~0u, ~0u, ~0u};                                        \
    _Pragma("unroll")                                                         \
    for (int j = 0; j < 16; ++j) {                                            \
      u32 key = wsel[B][r][j];                                                \
      if (key < top[3]) {                                                     \
        top[3] = key;                                                         \
        for (int z = 3; z > 0 && top[z] < top[z - 1]; --z) {                  \
          u32 tt = top[z]; top[z] = top[z - 1]; top[z - 1] = tt;              \
        }                                                                     \
      }                                                                       \
    }                                                                         \
    int rowg = (ST) * 32 + r;                                                 \
    uint4 ov; ov.x = ~top[0]; ov.y = ~top[1]; ov.z = ~top[2]; ov.w = ~top[3]; \
    *(uint4*)&ckey[((size_t)rowg * NCB + nb) * 4] = ov;                       \
  }

  for (int s = 0; s < 32; ++s) {
    int pb = s & 1;
    // barrier: stage s-1's wsel ds_writes drained (own-wave lgkm) and all
    // waves arrived. NO vmem drain — global loads are wave-private VGPR
    // loads and flow freely across the barrier.
    asm volatile("s_waitcnt lgkmcnt(0)" ::: "memory");
    __builtin_amdgcn_s_barrier();
    asm volatile("" ::: "memory");
    if (s > 0 && tid < 32) MERGE_EMIT(s - 1, pb ^ 1)

    const u16* As = A_ws + (size_t)s * 16384;   // stage s: 32 rows, 32 KB

    f32x4 ac[2];                       // [tile]; init = myc (per-comp const)
    ac[0] = mycv;
    ac[1] = mycv;
    __builtin_amdgcn_s_setprio(1);
#pragma unroll
    for (int cc = 0; cc < 16; ++cc) {
      // cache-direct A-frag reads (L1-broadcast across the 8 waves)
      bf16x8 a0 = *(const bf16x8*)(As + (size_t)cc * 512 + (size_t)l * 8);
      bf16x8 a1 = *(const bf16x8*)(As + 8192 + (size_t)cc * 512 + (size_t)l * 8);
      // SWAPPED operands: W as A-operand (comps = M), rows as B-operand (N)
      ac[0] = __builtin_amdgcn_mfma_f32_16x16x32_bf16(wf[cc], a0, ac[0], 0, 0, 0);
      ac[1] = __builtin_amdgcn_mfma_f32_16x16x32_bf16(wf[cc], a1, ac[1], 0, 0, 0);
    }
    __builtin_amdgcn_s_setprio(0);

    // selection: lane holds 4 comps (q*4+i) of x-row t*16+p.
    // scores are the ac values directly (all <= -235 < 0): unsigned MIN = best.
#define UMIN(a, b) ((a) < (b) ? (a) : (b))
#define UMAX(a, b) ((a) < (b) ? (b) : (a))
#pragma unroll
    for (int t = 0; t < 2; ++t) {
      u32 k0 = (__float_as_uint(ac[t][0]) & 0xFFFFFF00u) | (kid0 + 0);
      u32 k1 = (__float_as_uint(ac[t][1]) & 0xFFFFFF00u) | (kid0 + 1);
      u32 k2 = (__float_as_uint(ac[t][2]) & 0xFFFFFF00u) | (kid0 + 2);
      u32 k3 = (__float_as_uint(ac[t][3]) & 0xFFFFFF00u) | (kid0 + 3);
      // in-register top-2-of-4
      u32 l0 = UMIN(k0, k1), h0 = UMAX(k0, k1);
      u32 l1 = UMIN(k2, k3), h1 = UMAX(k2, k3);
      u32 m1 = UMIN(l0, l1), m2 = UMIN(UMAX(l0, l1), UMIN(h0, h1));
      // merge across the 4 q-lanes holding the same x-row: xor16 then xor32
      {
        u32 o1 = (u32)__shfl_xor((int)m1, 16);
        u32 o2 = (u32)__shfl_xor((int)m2, 16);
        u32 lo = UMIN(m1, o1), hi = UMAX(m1, o1), mn = UMIN(m2, o2);
        m1 = lo; m2 = UMIN(hi, mn);
      }
      {
        u32 o1 = (u32)__shfl_xor((int)m1, 32);
        u32 o2 = (u32)__shfl_xor((int)m2, 32);
        u32 lo = UMIN(m1, o1), hi = UMAX(m1, o1), mn = UMIN(m2, o2);
        m1 = lo; m2 = UMIN(hi, mn);
      }
      if (q == 0) {
        int r = t * 16 + p;
        wsel[pb][r][w * 2] = m1;
        wsel[pb][r][w * 2 + 1] = m2;
      }
    }
#undef UMIN
#undef UMAX
  }
  __syncthreads();
  if (tid < 32) MERGE_EMIT(31, 1)
#undef MERGE_EMIT
}

// ---------------------------------------------------------------------------
// Kernel 3: per-row finalize. 2048 keys -> 4 parallel per-wave exact top-16
// via u32 ext-keys + DPP/shfl arg-max; exact fp32 lp for 64; exact top-32 +
// softmax; weighted gather.
__global__ __launch_bounds__(256)
void finalize(const float* __restrict__ x, const float* __restrict__ mean,
              const float* __restrict__ stdd, const float* __restrict__ outs,
              const u32* __restrict__ ckey, float* __restrict__ out) {
  __shared__ u32 cksh[2048];
  __shared__ float xr[256];
  __shared__ float part[256];
  __shared__ int selk[64];
  __shared__ float ew[32];
  __shared__ int kf[32];
  __shared__ float invs_sh;
  int tid = threadIdx.x, l = tid & 63, v = tid >> 6;
  int row = blockIdx.x;

  for (int i = tid; i < 2048; i += 256)
    cksh[i] = ckey[(size_t)row * 2048 + i];
  xr[tid] = x[(size_t)row * DDIM + tid];
  __syncthreads();

  // 64-lane max reduce on u32 (4 DPP rotations + 2 shfl)
#define REDUCE_MAX(m)                                                         \
  {                                                                           \
    u32 o;                                                                    \
    o = (u32)__builtin_amdgcn_mov_dpp((int)m, DPP_ROR1, 0xf, 0xf, false);     \
    m = m > o ? m : o;                                                        \
    o = (u32)__builtin_amdgcn_mov_dpp((int)m, DPP_ROR2, 0xf, 0xf, false);     \
    m = m > o ? m : o;                                                        \
    o = (u32)__builtin_amdgcn_mov_dpp((int)m, DPP_ROR4, 0xf, 0xf, false);     \
    m = m > o ? m : o;                                                        \
    o = (u32)__builtin_amdgcn_mov_dpp((int)m, DPP_ROR8, 0xf, 0xf, false);     \
    m = m > o ? m : o;                                                        \
    o = (u32)__shfl_xor((int)m, 16); m = m > o ? m : o;                       \
    o = (u32)__shfl_xor((int)m, 32); m = m > o ? m : o;                       \
  }

  {  // wave v: exact top-16 of its 512 cands
    u32 ext[8];
#pragma unroll
    for (int i = 0; i < 8; ++i) {
      int j = v * 512 + i * 64 + l;
      ext[i] = (cksh[j] & 0xFFFFFE00u) | ((u32)l << 3) | (u32)i;
    }
#define CSW(a, b) { if (ext[a] < ext[b]) { u32 t = ext[a]; ext[a] = ext[b]; ext[b] = t; } }
    CSW(0,1) CSW(2,3) CSW(4,5) CSW(6,7)
    CSW(0,2) CSW(1,3) CSW(4,6) CSW(5,7)
    CSW(1,2) CSW(5,6)
    CSW(0,4) CSW(1,5) CSW(2,6) CSW(3,7)
    CSW(2,4) CSW(3,5)
    CSW(1,2) CSW(3,4) CSW(5,6)
#undef CSW
    for (int it = 0; it < 16; ++it) {
      u32 m = ext[0];
      REDUCE_MAX(m)
      if (m == ext[0]) {
#pragma unroll
        for (int z = 0; z < 7; ++z) ext[z] = ext[z + 1];
        ext[7] = 0;
      }
      if (l == 0) {
        int wl = (int)((m >> 3) & 63u), wi = (int)(m & 7u);
        int j = v * 512 + wi * 64 + wl;
        selk[v * 16 + it] = (int)((u32)(j >> 2) * 128u + (~cksh[j] & 0x7Fu));
      }
    }
  }
  __syncthreads();

  {  // exact fp32 lp for 64 cands, 4 threads each (rcpf: ~1e-7 rel, safe)
    int j = tid >> 2, qq = tid & 3;
    int k = selk[j];
    const float* mr = mean + (size_t)k * DDIM + qq * 64;
    const float* sr = stdd + (size_t)k * DDIM + qq * 64;
    float s2 = 0.f, ls = 0.f;
    for (int i = 0; i < 16; ++i) {
      float4 m4 = *(const float4*)(mr + 4 * i);
      float4 s4 = *(const float4*)(sr + 4 * i);
      float4 x4 = *(const float4*)(&xr[qq * 64 + 4 * i]);
      { float is = __builtin_amdgcn_rcpf(s4.x); float df = (x4.x - m4.x) * is; s2 += df * df; ls += __logf(s4.x); }
      { float is = __builtin_amdgcn_rcpf(s4.y); float df = (x4.y - m4.y) * is; s2 += df * df; ls += __logf(s4.y); }
      { float is = __builtin_amdgcn_rcpf(s4.z); float df = (x4.z - m4.z) * is; s2 += df * df; ls += __logf(s4.z); }
      { float is = __builtin_amdgcn_rcpf(s4.w); float df = (x4.w - m4.w) * is; s2 += df * df; ls += __logf(s4.w); }
    }
    part[tid] = -0.5f * s2 - ls;
  }
  __syncthreads();

  if (tid < 64) {                      // exact top-32 + softmax (wave 0)
    float lp0 = part[l * 4] + part[l * 4 + 1] + part[l * 4 + 2] +
                part[l * 4 + 3] - LOG2PI_TERM;
    u32 ext = (fkey(lp0) & 0xFFFFFFC0u) | (u32)l;
    float maxlp = 0.f, ssum = 0.f;
    for (int it = 0; it < 32; ++it) {
      u32 m = ext;
      REDUCE_MAX(m)
      int j = (int)(m & 63u);
      u32 vb = m & 0xFFFFFFC0u;
      vb ^= (vb >> 31) ? 0x80000000u : 0xFFFFFFFFu;
      float lp = __uint_as_float(vb);
      if (it == 0) maxlp = lp;
      float e = __expf(lp - maxlp);
      ssum += e;
      if (l == 0) { ew[it] = e; kf[it] = selk[j]; }
      if (j == l) ext = 0;
    }
    if (l == 0) invs_sh = 1.0f / ssum;
  }
  __syncthreads();
#undef REDUCE_MAX

  {  // weighted gather: one output element per thread
    float a = 0.f;
    for (int i = 0; i < 32; ++i)
      a += ew[i] * outs[(size_t)kf[i] * ODIM + tid];
    out[(size_t)row * ODIM + tid] = a * invs_sh;
  }
}

// ---------------------------------------------------------------------------
extern "C" void kernel_launch(void* const* d_in, const int* in_sizes, int n_in,
                              void* d_out, int out_size, void* d_ws, size_t ws_size,
                              hipStream_t stream) {
  const float* x = (const float*)d_in[0];
  const float* mean = (const float*)d_in[1];
  const float* stdd = (const float*)d_in[2];
  const float* outs = (const float*)d_in[3];
  char* ws = (char*)d_ws;
  u16* A_ws = (u16*)(ws + WS_A);
  u32* ckey = (u32*)(ws + WS_KEY);

  prep_A<<<64, 256, 0, stream>>>(x, A_ws);
  main_gemm<<<NBLK, 512, 0, stream>>>(A_ws, mean, stdd, ckey);
  finalize<<<BROWS, 256, 0, stream>>>(x, mean, stdd, outs, ckey,
                                      (float*)d_out);
}

// Round 7
// 338.838 us; speedup vs baseline: 1.1541x; 1.1435x over previous
//
#include <hip/hip_runtime.h>
#include <stdint.h>

// Problem constants
#define KCOMP 65536
#define DDIM  256
#define ODIM  256
#define BROWS 1024
#define NCB   1024           // comp-blocks: KCOMP / 64 comps per block
#define LOG2PI_TERM 235.2482645f   // 0.5 * D * ln(2*pi)

typedef float f32x4 __attribute__((ext_vector_type(4)));
typedef __bf16 bf16x8 __attribute__((ext_vector_type(8)));
typedef unsigned int u32;
typedef unsigned long long u64;
typedef unsigned short u16;

typedef __attribute__((address_space(1))) const u32 gconst_u32;
typedef __attribute__((address_space(3))) u32 lds_u32;

__device__ __forceinline__ u16 f2bf(float f) {
  u32 b = __float_as_uint(f);
  b += 0x7FFFu + ((b >> 16) & 1u);
  return (u16)(b >> 16);
}
// monotone float->u32 key (finalize only — main_gemm scores are all-negative
// so raw bits with unsigned-MIN are already order-correct)
__device__ __forceinline__ u32 fkey(float f) {
  u32 b = __float_as_uint(f);
  return b ^ ((b >> 31) ? 0xFFFFFFFFu : 0x80000000u);
}

// DPP row_ror:n (rotate within 16-lane rows) — used by finalize's reductions.
#define DPP_ROR1 0x121
#define DPP_ROR2 0x122
#define DPP_ROR4 0x124
#define DPP_ROR8 0x128

// ws layout (bytes). Total ~9 MB.
#define WS_A     0                          // 1 MB  A frag-linear [64 tile][16 cc][64 lane][16B]
#define WS_KEY   (1u << 20)                 // 8 MB  cand keys [1024 row][1024 cb][2]

// ---------------------------------------------------------------------------
// Kernel 1: A features. kappa=2d -> x_d^2 ; kappa=2d+1 -> -2 x_d (MFMA A layout).
__global__ void prep_A(const float* __restrict__ x, u16* __restrict__ A) {
  int l = threadIdx.x & 63;
  int wv = threadIdx.x >> 6;
  int t = blockIdx.x;                 // m16 tile 0..63
  int row = t * 16 + (l & 15);
  for (int u = 0; u < 4; ++u) {
    int cc = wv * 4 + u;              // 0..15
    int d0 = cc * 16 + ((l >> 4) << 2);
    float4 xv = *(const float4*)(x + (size_t)row * DDIM + d0);
    float xs[4] = {xv.x, xv.y, xv.z, xv.w};
    uint4 v;
    u32 wds[4];
    for (int e = 0; e < 4; ++e)
      wds[e] = (u32)f2bf(xs[e] * xs[e]) | ((u32)f2bf(-2.0f * xs[e]) << 16);
    v.x = wds[0]; v.y = wds[1]; v.z = wds[2]; v.w = wds[3];
    *(uint4*)(A + ((size_t)(t * 16 + cc) * 64 + l) * 8) = v;
  }
}

// ---------------------------------------------------------------------------
// Kernel 2: main GEMM + fused W-conversion + fused selection.
// ROUND-12 CHANGE (cut per-wave LDS reads at FULL occupancy): six rounds fit
// the model "stage wall = per-CU LDS demand (waves x rows-read x 64B) +
// latency exposure". r1/r5 cut demand but dropped to 2 waves/SIMD (exposed);
// r2 kept 4/SIMD but read all 32 rows/wave; r6 proved L1 (64 B/cyc) < LDS.
// The never-run quadrant: fewer reads/wave AND 4 waves/SIMD AND 2 blocks/CU.
// Achieved by shrinking comps/block to 64: grid 1024, block = 8 waves; wave
// (rt = w>>2 row-half, cg = w&3 comp-group of 16 -> wf[16] = 64 VGPR).
// Per wave per stage: 16 ds_read_b128 + 16 MFMA (two 8-deep chains) —
// per-CU LDS demand 512 KB -> 128 KB per stage at unchanged 16 waves/CU.
// Selection: top-2-of-4 + 2 shfl merges; block emits top-2 per 64 comps
// (2048 cands/row total, same finalize load as before, finer granularity).
// Barrier/prologue/key format = r2's proven code.
__global__ __launch_bounds__(512, 4)
void main_gemm(const u16* __restrict__ A_ws, const float* __restrict__ mean,
               const float* __restrict__ stdd, u32* __restrict__ ckey) {
  // union: [0,66560) = per-wave conversion scratch (8 x 8320 B) in prologue,
  //        [0,65536) = A double-buffer (2 bufs x 32 cells x 1 KB) in main loop
  __shared__ __align__(16) char lds_raw[66560];
  __shared__ u32 wsel[2][32][9];       // [buf][row][4 comp-groups x 2 + pad]
  int tid = threadIdx.x, l = tid & 63, w = tid >> 6;   // w in [0,8)
  int nb = blockIdx.x;                 // comp-block 0..1023 (64 comps each)
  int p = l & 15, q = l >> 4;
  int rt = w >> 2;                     // row-half of the 32-row stage (16 rows)
  int cg = w & 3;                      // comp-group 0..3 (16 comps)

  u32 kid0 = (u32)(cg * 16 + q * 4);   // local comp id base (0..63)

  // ---- prologue: build wf[16] B-frags (pre-scaled by -0.5) + mycv ----
  // two rounds of 8 comps each through an 8-comp scratch (8320 B/wave).
  // Waves w and w+4 convert the same comps (redundant, cache-friendly).
  bf16x8 wf[16];
  float myc0;
  f32x4 mycv;
  {
    u32* scr = (u32*)(lds_raw + w * 8320);   // [8 comps][260 dwords] padded
    int p8 = l & 7, q8 = l >> 3;             // q8 in [0,8): 32-dim eighth
#pragma unroll
    for (int rr = 0; rr < 2; ++rr) {
      int comp = (nb * 4 + cg) * 16 + rr * 8 + p8;
      const float* mrow = mean + (size_t)comp * DDIM + q8 * 32;
      const float* srow = stdd + (size_t)comp * DDIM + q8 * 32;
      float gsum = 0.f;
#pragma unroll
      for (int i = 0; i < 8; ++i) {
        float4 m4 = *(const float4*)(mrow + 4 * i);
        float4 s4 = *(const float4*)(srow + 4 * i);
        float ms[4] = {m4.x, m4.y, m4.z, m4.w};
        float ss[4] = {s4.x, s4.y, s4.z, s4.w};
        u32 wd[4];
#pragma unroll
        for (int e = 0; e < 4; ++e) {
          float iv = __builtin_amdgcn_rcpf(ss[e] * ss[e]);
          float miv = ms[e] * iv;
          // store -0.5*iv | -0.5*miv so dot(A,W) = -0.5*quad directly
          wd[e] = (u32)f2bf(-0.5f * iv) | ((u32)f2bf(-0.5f * miv) << 16);
          gsum -= 0.5f * ms[e] * miv + __logf(ss[e]);
        }
        uint4 v; v.x = wd[0]; v.y = wd[1]; v.z = wd[2]; v.w = wd[3];
        *(uint4*)(scr + p8 * 260 + q8 * 32 + i * 4) = v;   // [comp][dim]
      }
      // sum the 8 dim-eighth partials of comp p8 (lanes sharing l&7)
      gsum += __shfl_xor(gsum, 8);
      gsum += __shfl_xor(gsum, 16);
      gsum += __shfl_xor(gsum, 32);
      // lanes whose comp (p = l&15) lives in this round read their frags now
      // (wave-local in-order LDS; round rr+1 overwrites the scratch)
      if ((p >> 3) == rr) {
        myc0 = gsum - LOG2PI_TERM;
#pragma unroll
        for (int cc = 0; cc < 16; ++cc)
          wf[cc] = *(const bf16x8*)(scr + (p & 7) * 260 + cc * 16 + q * 4);
      }
    }
    // redistribute myc: lane (q,p) needs myc of comps q*4+i (held by lane q*4+i)
#pragma unroll
    for (int i = 0; i < 4; ++i)
      mycv[i] = __shfl(myc0, q * 4 + i);
  }
  __syncthreads();                     // scratch region now reused as Ash

#define ASHP(B, CELL) (lds_raw + ((size_t)(B) * 32 + (CELL)) * 1024)

  // stage S (2 m16-tiles = 32 cells of 1 KB) into buf B; wave stages 4 cells
#define ISSUE(S, B)                                                           \
  {                                                                           \
    _Pragma("unroll")                                                         \
    for (int u = 0; u < 4; ++u) {                                             \
      int cell = w * 4 + u;                                                   \
      const u16* gsrc = A_ws +                                                \
        ((size_t)((S) * 2 + (cell >> 4)) * 16 + (cell & 15)) * 512            \
        + (size_t)l * 8;                                                      \
      __builtin_amdgcn_global_load_lds((gconst_u32*)gsrc,                     \
          (lds_u32*)ASHP(B, cell), 16, 0, 0);                                 \
    }                                                                         \
  }

  // merge 8 wsel keys (min = best) -> 2 smallest for 32 rows; emit inverted
#define MERGE_EMIT(ST, B)                                                     \
  {                                                                           \
    int r = tid;                                                              \
    u32 b1 = ~0u, b2 = ~0u;                                                   \
    _Pragma("unroll")                                                         \
    for (int j = 0; j < 8; ++j) {                                             \
      u32 key = wsel[B][r][j];                                                \
      if (key < b1) { b2 = b1; b1 = key; }                                    \
      else if (key < b2) { b2 = key; }                                        \
    }                                                                         \
    int rowg = (ST) * 32 + r;                                                 \
    uint2 ov; ov.x = ~b1; ov.y = ~b2;                                         \
    *(uint2*)&ckey[((size_t)rowg * NCB + nb) * 2] = ov;                       \
  }

  ISSUE(0, 0)
  for (int s = 0; s < 32; ++s) {
    int pb = s & 1;
    __syncthreads();                   // buf pb staged; wsel[pb^1] complete
    if (s < 31) ISSUE(s + 1, pb ^ 1)
    if (s > 0 && tid < 32) MERGE_EMIT(s - 1, pb ^ 1)

    // two independent 8-deep MFMA chains over the wave's 16-row half
    f32x4 aca = mycv;                  // chain A carries the myc init
    f32x4 acb = (f32x4){0.f, 0.f, 0.f, 0.f};
    __builtin_amdgcn_s_setprio(1);
#pragma unroll
    for (int cc = 0; cc < 8; ++cc) {
      bf16x8 a0 = *(const bf16x8*)(ASHP(pb, rt * 16 + cc) + (size_t)l * 16);
      bf16x8 a1 = *(const bf16x8*)(ASHP(pb, rt * 16 + 8 + cc) + (size_t)l * 16);
      // SWAPPED operands: W as A-operand (comps = M), rows as B-operand (N)
      aca = __builtin_amdgcn_mfma_f32_16x16x32_bf16(wf[cc], a0, aca, 0, 0, 0);
      acb = __builtin_amdgcn_mfma_f32_16x16x32_bf16(wf[8 + cc], a1, acb, 0, 0, 0);
    }
    __builtin_amdgcn_s_setprio(0);
    f32x4 ac;
    ac[0] = aca[0] + acb[0]; ac[1] = aca[1] + acb[1];
    ac[2] = aca[2] + acb[2]; ac[3] = aca[3] + acb[3];

    // selection: lane holds 4 comps (q*4+i) of x-row rt*16+p.
    // scores are the ac values directly (all <= -235 < 0): unsigned MIN = best.
#define UMIN(a, b) ((a) < (b) ? (a) : (b))
#define UMAX(a, b) ((a) < (b) ? (b) : (a))
    {
      u32 k0 = (__float_as_uint(ac[0]) & 0xFFFFFF00u) | (kid0 + 0);
      u32 k1 = (__float_as_uint(ac[1]) & 0xFFFFFF00u) | (kid0 + 1);
      u32 k2 = (__float_as_uint(ac[2]) & 0xFFFFFF00u) | (kid0 + 2);
      u32 k3 = (__float_as_uint(ac[3]) & 0xFFFFFF00u) | (kid0 + 3);
      // in-register top-2-of-4
      u32 l0 = UMIN(k0, k1), h0 = UMAX(k0, k1);
      u32 l1 = UMIN(k2, k3), h1 = UMAX(k2, k3);
      u32 m1 = UMIN(l0, l1), m2 = UMIN(UMAX(l0, l1), UMIN(h0, h1));
      // merge across the 4 q-lanes holding the same x-row: xor16 then xor32
      {
        u32 o1 = (u32)__shfl_xor((int)m1, 16);
        u32 o2 = (u32)__shfl_xor((int)m2, 16);
        u32 lo = UMIN(m1, o1), hi = UMAX(m1, o1), mn = UMIN(m2, o2);
        m1 = lo; m2 = UMIN(hi, mn);
      }
      {
        u32 o1 = (u32)__shfl_xor((int)m1, 32);
        u32 o2 = (u32)__shfl_xor((int)m2, 32);
        u32 lo = UMIN(m1, o1), hi = UMAX(m1, o1), mn = UMIN(m2, o2);
        m1 = lo; m2 = UMIN(hi, mn);
      }
      if (q == 0) {
        int r = rt * 16 + p;
        wsel[pb][r][cg * 2] = m1;
        wsel[pb][r][cg * 2 + 1] = m2;
      }
    }
#undef UMIN
#undef UMAX
  }
  __syncthreads();
  if (tid < 32) MERGE_EMIT(31, 1)
#undef ISSUE
#undef MERGE_EMIT
#undef ASHP
}

// ---------------------------------------------------------------------------
// Kernel 3: per-row finalize. 2048 keys (2 per 64-comp block) -> 4 parallel
// per-wave exact top-16 via u32 ext-keys + DPP/shfl arg-max; exact fp32 lp
// for 64; exact top-32 + softmax; weighted gather.
__global__ __launch_bounds__(256)
void finalize(const float* __restrict__ x, const float* __restrict__ mean,
              const float* __restrict__ stdd, const float* __restrict__ outs,
              const u32* __restrict__ ckey, float* __restrict__ out) {
  __shared__ u32 cksh[2048];
  __shared__ float xr[256];
  __shared__ float part[256];
  __shared__ int selk[64];
  __shared__ float ew[32];
  __shared__ int kf[32];
  __shared__ float invs_sh;
  int tid = threadIdx.x, l = tid & 63, v = tid >> 6;
  int row = blockIdx.x;

  for (int i = tid; i < 2048; i += 256)
    cksh[i] = ckey[(size_t)row * 2048 + i];
  xr[tid] = x[(size_t)row * DDIM + tid];
  __syncthreads();

  // 64-lane max reduce on u32 (4 DPP rotations + 2 shfl)
#define REDUCE_MAX(m)                                                         \
  {                                                                           \
    u32 o;                                                                    \
    o = (u32)__builtin_amdgcn_mov_dpp((int)m, DPP_ROR1, 0xf, 0xf, false);     \
    m = m > o ? m : o;                                                        \
    o = (u32)__builtin_amdgcn_mov_dpp((int)m, DPP_ROR2, 0xf, 0xf, false);     \
    m = m > o ? m : o;                                                        \
    o = (u32)__builtin_amdgcn_mov_dpp((int)m, DPP_ROR4, 0xf, 0xf, false);     \
    m = m > o ? m : o;                                                        \
    o = (u32)__builtin_amdgcn_mov_dpp((int)m, DPP_ROR8, 0xf, 0xf, false);     \
    m = m > o ? m : o;                                                        \
    o = (u32)__shfl_xor((int)m, 16); m = m > o ? m : o;                       \
    o = (u32)__shfl_xor((int)m, 32); m = m > o ? m : o;                       \
  }

  {  // wave v: exact top-16 of its 512 cands
    u32 ext[8];
#pragma unroll
    for (int i = 0; i < 8; ++i) {
      int j = v * 512 + i * 64 + l;
      ext[i] = (cksh[j] & 0xFFFFFE00u) | ((u32)l << 3) | (u32)i;
    }
#define CSW(a, b) { if (ext[a] < ext[b]) { u32 t = ext[a]; ext[a] = ext[b]; ext[b] = t; } }
    CSW(0,1) CSW(2,3) CSW(4,5) CSW(6,7)
    CSW(0,2) CSW(1,3) CSW(4,6) CSW(5,7)
    CSW(1,2) CSW(5,6)
    CSW(0,4) CSW(1,5) CSW(2,6) CSW(3,7)
    CSW(2,4) CSW(3,5)
    CSW(1,2) CSW(3,4) CSW(5,6)
#undef CSW
    for (int it = 0; it < 16; ++it) {
      u32 m = ext[0];
      REDUCE_MAX(m)
      if (m == ext[0]) {
#pragma unroll
        for (int z = 0; z < 7; ++z) ext[z] = ext[z + 1];
        ext[7] = 0;
      }
      if (l == 0) {
        int wl = (int)((m >> 3) & 63u), wi = (int)(m & 7u);
        int j = v * 512 + wi * 64 + wl;
        // key j: comp-block j>>1 (64 comps), local id = low 6 bits inverted
        selk[v * 16 + it] = (int)((u32)(j >> 1) * 64u + (~cksh[j] & 0x3Fu));
      }
    }
  }
  __syncthreads();

  {  // exact fp32 lp for 64 cands, 4 threads each (rcpf: ~1e-7 rel, safe)
    int j = tid >> 2, qq = tid & 3;
    int k = selk[j];
    const float* mr = mean + (size_t)k * DDIM + qq * 64;
    const float* sr = stdd + (size_t)k * DDIM + qq * 64;
    float s2 = 0.f, ls = 0.f;
    for (int i = 0; i < 16; ++i) {
      float4 m4 = *(const float4*)(mr + 4 * i);
      float4 s4 = *(const float4*)(sr + 4 * i);
      float4 x4 = *(const float4*)(&xr[qq * 64 + 4 * i]);
      { float is = __builtin_amdgcn_rcpf(s4.x); float df = (x4.x - m4.x) * is; s2 += df * df; ls += __logf(s4.x); }
      { float is = __builtin_amdgcn_rcpf(s4.y); float df = (x4.y - m4.y) * is; s2 += df * df; ls += __logf(s4.y); }
      { float is = __builtin_amdgcn_rcpf(s4.z); float df = (x4.z - m4.z) * is; s2 += df * df; ls += __logf(s4.z); }
      { float is = __builtin_amdgcn_rcpf(s4.w); float df = (x4.w - m4.w) * is; s2 += df * df; ls += __logf(s4.w); }
    }
    part[tid] = -0.5f * s2 - ls;
  }
  __syncthreads();

  if (tid < 64) {                      // exact top-32 + softmax (wave 0)
    float lp0 = part[l * 4] + part[l * 4 + 1] + part[l * 4 + 2] +
                part[l * 4 + 3] - LOG2PI_TERM;
    u32 ext = (fkey(lp0) & 0xFFFFFFC0u) | (u32)l;
    float maxlp = 0.f, ssum = 0.f;
    for (int it = 0; it < 32; ++it) {
      u32 m = ext;
      REDUCE_MAX(m)
      int j = (int)(m & 63u);
      u32 vb = m & 0xFFFFFFC0u;
      vb ^= (vb >> 31) ? 0x80000000u : 0xFFFFFFFFu;
      float lp = __uint_as_float(vb);
      if (it == 0) maxlp = lp;
      float e = __expf(lp - maxlp);
      ssum += e;
      if (l == 0) { ew[it] = e; kf[it] = selk[j]; }
      if (j == l) ext = 0;
    }
    if (l == 0) invs_sh = 1.0f / ssum;
  }
  __syncthreads();
#undef REDUCE_MAX

  {  // weighted gather: one output element per thread
    float a = 0.f;
    for (int i = 0; i < 32; ++i)
      a += ew[i] * outs[(size_t)kf[i] * ODIM + tid];
    out[(size_t)row * ODIM + tid] = a * invs_sh;
  }
}

// ---------------------------------------------------------------------------
extern "C" void kernel_launch(void* const* d_in, const int* in_sizes, int n_in,
                              void* d_out, int out_size, void* d_ws, size_t ws_size,
                              hipStream_t stream) {
  const float* x = (const float*)d_in[0];
  const float* mean = (const float*)d_in[1];
  const float* stdd = (const float*)d_in[2];
  const float* outs = (const float*)d_in[3];
  char* ws = (char*)d_ws;
  u16* A_ws = (u16*)(ws + WS_A);
  u32* ckey = (u32*)(ws + WS_KEY);

  prep_A<<<64, 256, 0, stream>>>(x, A_ws);
  main_gemm<<<NCB, 512, 0, stream>>>(A_ws, mean, stdd, ckey);
  finalize<<<BROWS, 256, 0, stream>>>(x, mean, stdd, outs, ckey,
                                      (float*)d_out);
}